// Round 15
// baseline (81.566 us; speedup 1.0000x reference)
//
#include <hip/hip_runtime.h>
#include <math.h>

#define GROUPS 4
#define DCH    64
#define NBATCH 32
#define CTOT   256
#define HW     3136
#define CHW    (CTOT*HW)        /* 802816 */
#define MTOT   (NBATCH*HW)      /* 100352 */
#define PB     196              /* partial k-blocks per group */
#define EPSV   1e-5f

typedef __attribute__((ext_vector_type(8))) short bf16x8;
typedef __attribute__((ext_vector_type(4))) float f32x4;

__device__ __forceinline__ f32x4 mfma16(bf16x8 a, bf16x8 b, f32x4 c) {
    return __builtin_amdgcn_mfma_f32_16x16x32_bf16(a, b, c, 0, 0, 0);
}

// truncation split: x = hi + lo (exact), bf16(hi), bf16(lo); err <= 2^-16 |x|
__device__ __forceinline__ void split2(float x, short& h, short& l) {
    union { float f; unsigned u; } c; c.f = x;
    h = (short)(c.u >> 16);
    union { unsigned u; float f; } hm; hm.u = c.u & 0xFFFF0000u;
    union { float f; unsigned u; } lo; lo.f = x - hm.f;
    l = (short)(lo.u >> 16);
}

__device__ __forceinline__ void load_slab(const float* bp, float dst[16]) {
    float4 a0 = *reinterpret_cast<const float4*>(bp);
    float4 a1 = *reinterpret_cast<const float4*>(bp + 4);
    float4 b0 = *reinterpret_cast<const float4*>(bp + 32);
    float4 b1 = *reinterpret_cast<const float4*>(bp + 36);
    dst[0]=a0.x; dst[1]=a0.y; dst[2]=a0.z;  dst[3]=a0.w;
    dst[4]=a1.x; dst[5]=a1.y; dst[6]=a1.z;  dst[7]=a1.w;
    dst[8]=b0.x; dst[9]=b0.y; dst[10]=b0.z; dst[11]=b0.w;
    dst[12]=b1.x; dst[13]=b1.y; dst[14]=b1.z; dst[15]=b1.w;
}

// ---------------------------------------------------------------------------
// K1: per-group partial Gram (R14 form — best measured). Wave (tr,par) loads
// only its own 16-row slab, shares packed hi/lo fragments via TRUE
// double-buffered frag LDS (2 x 32KB halves, fb=(t&1)*8192), ONE barrier
// per step. 66KB LDS -> 2 blocks/CU.
// ---------------------------------------------------------------------------
__global__ __launch_bounds__(512) void k1_gram(const float* __restrict__ X,
                                               float* __restrict__ pGram,
                                               float* __restrict__ pSum)
{
    constexpr int KPB = MTOT / PB;      // 512 cols per block
    constexpr int NST = KPB / 128;      // 4 steps (even -> final fb = 8192)
    const int pb   = blockIdx.x;
    const int g    = blockIdx.y;
    const int tid  = threadIdx.x;       // 0..511
    const int w    = tid >> 6;
    const int lane = tid & 63;
    const int tr   = w & 3;             // slab this wave owns
    const int par  = w >> 2;            // 64-col half of the 128-col step
    const int lr   = lane & 15;
    const int q    = lane >> 4;

    __shared__ float smem[16384];       // 2 x 32KB frag buffers; epilogue overlays [0..8191]
    __shared__ float rsum[2][64];

    f32x4 acc[4];
#pragma unroll
    for (int c = 0; c < 4; ++c) acc[c] = (f32x4)(0.f);
    float sumv = 0.f;

    const float* Xg  = X + (size_t)g * DCH * HW;
    const int    row = 16 * tr + lr;

    float xv[2][16];
    // prologue: issue step 0
    {
        const int kk = pb * KPB + par * 64;
        const int n  = kk / HW;
        const int s  = kk - n * HW;
        load_slab(Xg + (size_t)n * CHW + (size_t)row * HW + s + q * 8, xv[0]);
    }

#pragma unroll
    for (int t = 0; t < NST; ++t) {
        const int fb = (t & 1) * 8192;  // this step's frag buffer half
        // 1) issue step t+1 loads first (independent of step-t pack)
        if (t + 1 < NST) {
            const int kk = pb * KPB + (t + 1) * 128 + par * 64;
            const int n  = kk / HW;
            const int s  = kk - n * HW;
            load_slab(Xg + (size_t)n * CHW + (size_t)row * HW + s + q * 8,
                      xv[(t + 1) & 1]);
        }
        // 2) pack own fragments for step t
        bf16x8 ah[2], al[2];
#pragma unroll
        for (int ks = 0; ks < 2; ++ks) {
#pragma unroll
            for (int j = 0; j < 8; ++j) {
                float x = xv[t & 1][ks * 8 + j];
                sumv += x;
                short h, l; split2(x, h, l);
                ah[ks][j] = h; al[ks][j] = l;
            }
        }
        // 3) publish: slot = ((par*4+slab)*2+ks)*2+hl, 1KB/slot, lane-linear
#pragma unroll
        for (int ks = 0; ks < 2; ++ks) {
            *reinterpret_cast<bf16x8*>(&smem[fb + (((par*4+tr)*2+ks)*2+0)*256 + lane*4]) = ah[ks];
            *reinterpret_cast<bf16x8*>(&smem[fb + (((par*4+tr)*2+ks)*2+1)*256 + lane*4]) = al[ks];
        }
        __syncthreads();
        // 4) consume all 4 slabs (no trailing barrier: next publish -> other half)
#pragma unroll
        for (int c = 0; c < 4; ++c) {
#pragma unroll
            for (int ks = 0; ks < 2; ++ks) {
                bf16x8 bh = *reinterpret_cast<const bf16x8*>(
                    &smem[fb + (((par*4+c)*2+ks)*2+0)*256 + lane*4]);
                bf16x8 bl = *reinterpret_cast<const bf16x8*>(
                    &smem[fb + (((par*4+c)*2+ks)*2+1)*256 + lane*4]);
                acc[c] = mfma16(ah[ks], bh, acc[c]);
                acc[c] = mfma16(ah[ks], bl, acc[c]);
                acc[c] = mfma16(al[ks], bh, acc[c]);
            }
        }
    }

    // row sums: reduce over q-quarters
    sumv += __shfl_xor(sumv, 16);
    sumv += __shfl_xor(sumv, 32);
    if (q == 0) rsum[par][row] = sumv;

    // parity-split Gram partial into overlay [0..8191] — disjoint from the
    // final step's frag half (fb=8192 since NST even).
#pragma unroll
    for (int c = 0; c < 4; ++c) {
#pragma unroll
        for (int r = 0; r < 4; ++r) {
            smem[par * 4096 + (16 * tr + 4 * q + r) * 64 + 16 * c + lr] = acc[c][r];
        }
    }
    __syncthreads();

    float* pg = pGram + ((size_t)g * PB + pb) * 4096;
    for (int i = tid; i < 4096; i += 512) pg[i] = smem[i] + smem[4096 + i];
    if (tid < 64)
        pSum[((size_t)g * PB + pb) * 64 + tid] = rsum[0][tid] + rsum[1][tid];
}

// ---------------------------------------------------------------------------
// K2a1: first-level reduce of partials. Grid (64, 4, 7): block (cb,g,s)
// reduces 28 pbs (7 per thread-quarter, compile-time -> batched loads).
// ---------------------------------------------------------------------------
__global__ __launch_bounds__(256) void k2a1(const float* __restrict__ pGram,
                                            const float* __restrict__ pSum,
                                            float* __restrict__ pG2,
                                            float* __restrict__ pS2)
{
    constexpr int SLICE = PB / 7;       // 28
    const int cb  = blockIdx.x;   // 0..63
    const int g   = blockIdx.y;
    const int s   = blockIdx.z;   // 0..6
    const int tid = threadIdx.x;
    const int e = tid & 63, q = tid >> 6;
    __shared__ float red[4][64];
    __shared__ float red2[4][64];

    const float* pg = pGram + ((size_t)g * PB + s * SLICE + q) * 4096 + cb * 64 + e;
    float sum = 0.f;
#pragma unroll
    for (int i = 0; i < SLICE / 4; ++i)
        sum += pg[(size_t)i * 4 * 4096];
    red[q][e] = sum;
    if (cb == 0) {
        const float* ps = pSum + ((size_t)g * PB + s * SLICE + q) * 64 + e;
        float s2 = 0.f;
#pragma unroll
        for (int i = 0; i < SLICE / 4; ++i)
            s2 += ps[i * 4 * 64];
        red2[q][e] = s2;
    }
    __syncthreads();
    if (tid < 64) {
        pG2[((size_t)g * 7 + s) * 4096 + cb * 64 + tid] =
            red[0][tid] + red[1][tid] + red[2][tid] + red[3][tid];
        if (cb == 0)
            pS2[((size_t)g * 7 + s) * 64 + tid] =
                red2[0][tid] + red2[1][tid] + red2[2][tid] + red2[3][tid];
    }
}

// ---------------------------------------------------------------------------
// K2b: fused final-reduce + Newton-Schulz on the matrix pipe.
//  iter 1 closed-form; iters 2..5 shared-A stage1 (P2, PS) + stage2
//  P2*PS^T; Sn B-fragments hoisted to registers (loop-invariant).
// ---------------------------------------------------------------------------
__device__ __forceinline__ void packrow2(const float* __restrict__ M, int row, int q,
                                         bf16x8& h0, bf16x8& l0,
                                         bf16x8& h1, bf16x8& l1)
{
    const float* p = M + row * 68 + 8 * q;
    float4 a0 = *reinterpret_cast<const float4*>(p);
    float4 a1 = *reinterpret_cast<const float4*>(p + 4);
    float4 b0 = *reinterpret_cast<const float4*>(p + 32);
    float4 b1 = *reinterpret_cast<const float4*>(p + 36);
    float e0[8] = {a0.x, a0.y, a0.z, a0.w, a1.x, a1.y, a1.z, a1.w};
    float e1[8] = {b0.x, b0.y, b0.z, b0.w, b1.x, b1.y, b1.z, b1.w};
#pragma unroll
    for (int j = 0; j < 8; ++j) {
        short h, l;
        split2(e0[j], h, l); h0[j] = h; l0[j] = l;
        split2(e1[j], h, l); h1[j] = h; l1[j] = l;
    }
}

__global__ __launch_bounds__(256) void k2b_ns(const float* __restrict__ pG2,
                                              const float* __restrict__ pS2,
                                              const float* __restrict__ Wt,
                                              const float* __restrict__ Bs,
                                              float* __restrict__ Aout,
                                              float* __restrict__ Off)
{
    const int g   = blockIdx.x;
    const int tid = threadIdx.x;
    const int w = tid >> 6, lane = tid & 63, lr = lane & 15, q = lane >> 4;
    __shared__ float MP[64 * 68];
    __shared__ float MA[64 * 68];    // P2
    __shared__ float MB2[64 * 68];   // PS
    __shared__ float MS[64 * 68];    // Sn
    __shared__ float lmean[64];
    __shared__ float redm[1024];
    __shared__ float rtr_s;

    if (tid < 64) {
        float s2 = 0.f;
#pragma unroll
        for (int s = 0; s < 7; ++s) s2 += pS2[((size_t)g * 7 + s) * 64 + tid];
        lmean[tid] = s2 * (1.0f / (float)MTOT);
    }
    __syncthreads();
    for (int idx = tid; idx < 4096; idx += 256) {
        int d = idx >> 6, e = idx & 63;
        float sum = 0.f;
#pragma unroll
        for (int s = 0; s < 7; ++s) sum += pG2[((size_t)g * 7 + s) * 4096 + idx];
        float v = sum * (1.0f / (float)MTOT) - lmean[d] * lmean[e];
        if (d == e) v += EPSV;
        MS[d * 68 + e] = v;
    }
    __syncthreads();
    if (tid < 64) {
        float v = MS[tid * 68 + tid];
#pragma unroll
        for (int off = 32; off > 0; off >>= 1) v += __shfl_down(v, off);
        if (tid == 0) rtr_s = 1.f / v;
    }
    __syncthreads();
    const float rTr = rtr_s;
    for (int idx = tid; idx < 4096; idx += 256) {
        int d = idx >> 6, e = idx & 63;
        float sv = MS[d * 68 + e] * rTr;
        MS[d * 68 + e] = sv;
        MP[d * 68 + e] = ((d == e) ? 1.5f : 0.f) - 0.5f * sv;
    }
    __syncthreads();

    // hoist loop-invariant Sn B-fragments into registers
    bf16x8 snh0[4], snl0[4], snh1[4], snl1[4];
#pragma unroll
    for (int c = 0; c < 4; ++c)
        packrow2(MS, 16 * c + lr, q, snh0[c], snl0[c], snh1[c], snl1[c]);

    const int row_o = 16 * w + 4 * q;
    for (int it = 0; it < 4; ++it) {
        f32x4 a2[4], aS[4];
#pragma unroll
        for (int c = 0; c < 4; ++c) { a2[c] = (f32x4)(0.f); aS[c] = (f32x4)(0.f); }
        bf16x8 pah0, pal0, pah1, pal1;
        packrow2(MP, 16 * w + lr, q, pah0, pal0, pah1, pal1);
#pragma unroll
        for (int c = 0; c < 4; ++c) {
            bf16x8 bh0, bl0, bh1, bl1;
            packrow2(MP, 16 * c + lr, q, bh0, bl0, bh1, bl1);
            a2[c] = mfma16(pah0, bh0, a2[c]);
            a2[c] = mfma16(pah0, bl0, a2[c]);
            a2[c] = mfma16(pal0, bh0, a2[c]);
            a2[c] = mfma16(pah1, bh1, a2[c]);
            a2[c] = mfma16(pah1, bl1, a2[c]);
            a2[c] = mfma16(pal1, bh1, a2[c]);
            aS[c] = mfma16(pah0, snh0[c], aS[c]);
            aS[c] = mfma16(pah0, snl0[c], aS[c]);
            aS[c] = mfma16(pal0, snh0[c], aS[c]);
            aS[c] = mfma16(pah1, snh1[c], aS[c]);
            aS[c] = mfma16(pah1, snl1[c], aS[c]);
            aS[c] = mfma16(pal1, snh1[c], aS[c]);
        }
#pragma unroll
        for (int c = 0; c < 4; ++c)
#pragma unroll
            for (int r = 0; r < 4; ++r) {
                MA [(row_o + r) * 68 + 16 * c + lr] = a2[c][r];
                MB2[(row_o + r) * 68 + 16 * c + lr] = aS[c][r];
            }
        __syncthreads();

        f32x4 acc[4];
#pragma unroll
        for (int c = 0; c < 4; ++c) acc[c] = (f32x4)(0.f);
        bf16x8 qah0, qal0, qah1, qal1;
        packrow2(MA, 16 * w + lr, q, qah0, qal0, qah1, qal1);
#pragma unroll
        for (int c = 0; c < 4; ++c) {
            bf16x8 bh0, bl0, bh1, bl1;
            packrow2(MB2, 16 * c + lr, q, bh0, bl0, bh1, bl1);
            acc[c] = mfma16(qah0, bh0, acc[c]);
            acc[c] = mfma16(qah0, bl0, acc[c]);
            acc[c] = mfma16(qal0, bh0, acc[c]);
            acc[c] = mfma16(qah1, bh1, acc[c]);
            acc[c] = mfma16(qah1, bl1, acc[c]);
            acc[c] = mfma16(qal1, bh1, acc[c]);
        }
#pragma unroll
        for (int c = 0; c < 4; ++c)
#pragma unroll
            for (int r = 0; r < 4; ++r) {
                int o = (row_o + r) * 68 + 16 * c + lr;
                MP[o] = 1.5f * MP[o] - 0.5f * acc[c][r];
            }
        __syncthreads();
    }

    const float sc = sqrtf(rTr);
    const int i0 = (tid >> 4) << 2, j0 = (tid & 15) << 2;
#pragma unroll
    for (int i = 0; i < 4; ++i) {
        int d = i0 + i;
        float wv = Wt[g * 64 + d] * sc;
        float4 v;
        v.x = MP[d * 68 + j0 + 0] * wv;
        v.y = MP[d * 68 + j0 + 1] * wv;
        v.z = MP[d * 68 + j0 + 2] * wv;
        v.w = MP[d * 68 + j0 + 3] * wv;
        *reinterpret_cast<float4*>(Aout + g * 4096 + (d << 6) + j0) = v;
        redm[(d << 4) + (tid & 15)] =
            v.x * lmean[j0] + v.y * lmean[j0 + 1] + v.z * lmean[j0 + 2] + v.w * lmean[j0 + 3];
    }
    __syncthreads();
    if (tid < 64) {
        float s = 0.f;
#pragma unroll
        for (int qq = 0; qq < 16; ++qq) s += redm[(tid << 4) + qq];
        Off[g * 64 + tid] = Bs[g * 64 + tid] - s;
    }
}

// ---------------------------------------------------------------------------
// K3: out = A'(x) + off. R15 single change: x-fragments read DIRECTLY from
// global (16 b128/lane, 256B per 16-lane row, coalesced) — no LDS, no
// barrier, fewer total memory instructions than the staged form
// (16 vs 4+4+16+barrier). The 4x logical read redundancy across the
// block's waves is L2/L3-absorbed (R5 precedent: 4x logical -> FETCH
// unchanged). R12's failure (dword granularity) does not apply: b128.
// ---------------------------------------------------------------------------
__global__ __launch_bounds__(256) void k3_apply(const float* __restrict__ X,
                                                const float* __restrict__ Aout,
                                                const float* __restrict__ Off,
                                                float* __restrict__ Y)
{
    const int c    = blockIdx.x;        // 0..1567
    const int g    = blockIdx.y;
    const int tid  = threadIdx.x;
    const int w    = tid >> 6;          // output row block 16w
    const int lane = tid & 63;
    const int lr   = lane & 15;
    const int q    = lane >> 4;

    const int col0 = c * 64;            // never crosses sample (HW%64==0)
    const int n    = col0 / HW;
    const int s0   = col0 - n * HW;
    const float* Xg   = X + (size_t)g * DCH * HW;
    const float* base = Xg + (size_t)n * CHW + s0 + 4 * lr;

    // 1) issue ALL 16 x loads (per-lane 16B, coalesced per 16-lane row)
    float4 xv[16];
#pragma unroll
    for (int ks = 0; ks < 2; ++ks)
#pragma unroll
        for (int j8 = 0; j8 < 8; ++j8)
            xv[ks * 8 + j8] =
                *reinterpret_cast<const float4*>(base + (size_t)(32 * ks + 8 * q + j8) * HW);

    // 2) load+pack A' fragments and offsets under the x loads' shadow
    bf16x8 ah[2], al[2];
#pragma unroll
    for (int s = 0; s < 2; ++s) {
        const float* ap = Aout + g * 4096 + (16 * w + lr) * 64 + 32 * s + 8 * q;
        float4 v0 = *reinterpret_cast<const float4*>(ap);
        float4 v1 = *reinterpret_cast<const float4*>(ap + 4);
        float av[8] = {v0.x, v0.y, v0.z, v0.w, v1.x, v1.y, v1.z, v1.w};
#pragma unroll
        for (int j = 0; j < 8; ++j) {
            short h, l; split2(av[j], h, l);
            ah[s][j] = h; al[s][j] = l;
        }
    }
    float offv[4];
#pragma unroll
    for (int r = 0; r < 4; ++r) offv[r] = Off[g * 64 + 16 * w + 4 * q + r];
    __builtin_amdgcn_sched_barrier(0);

    // 3) pack + MFMA
    f32x4 accg[4];
#pragma unroll
    for (int j = 0; j < 4; ++j) accg[j] = (f32x4)(0.f);

#pragma unroll
    for (int ks = 0; ks < 2; ++ks) {
        bf16x8 bh[4], bl[4];
#pragma unroll
        for (int j8 = 0; j8 < 8; ++j8) {
            float4 v = xv[ks * 8 + j8];
            float vv[4] = {v.x, v.y, v.z, v.w};
#pragma unroll
            for (int jj = 0; jj < 4; ++jj) {
                short h, l; split2(vv[jj], h, l);
                bh[jj][j8] = h; bl[jj][j8] = l;
            }
        }
#pragma unroll
        for (int jj = 0; jj < 4; ++jj) {
            accg[jj] = mfma16(ah[ks], bh[jj], accg[jj]);
            accg[jj] = mfma16(ah[ks], bl[jj], accg[jj]);
            accg[jj] = mfma16(al[ks], bh[jj], accg[jj]);
        }
    }

    // 4) store
    float* yp = Y + (size_t)g * DCH * HW + (size_t)n * CHW + s0 + 4 * lr;
#pragma unroll
    for (int r = 0; r < 4; ++r) {
        int row = 16 * w + 4 * q + r;
        float4 o;
        o.x = accg[0][r] + offv[r];
        o.y = accg[1][r] + offv[r];
        o.z = accg[2][r] + offv[r];
        o.w = accg[3][r] + offv[r];
        *reinterpret_cast<float4*>(yp + (size_t)row * HW) = o;
    }
}

// ---------------------------------------------------------------------------
extern "C" void kernel_launch(void* const* d_in, const int* in_sizes, int n_in,
                              void* d_out, int out_size, void* d_ws, size_t ws_size,
                              hipStream_t stream)
{
    const float* X  = (const float*)d_in[0];
    const float* Wt = (const float*)d_in[1];
    const float* Bs = (const float*)d_in[2];
    float* Y  = (float*)d_out;
    float* ws = (float*)d_ws;

    float* pGram = ws;                                    // 4*PB*4096
    float* pSum  = pGram + (size_t)4 * PB * 4096;         // 4*PB*64
    float* pG2   = pSum  + (size_t)4 * PB * 64;           // 4*7*4096
    float* pS2   = pG2   + (size_t)4 * 7 * 4096;          // 4*7*64
    float* Aout  = pS2   + (size_t)4 * 7 * 64;            // 4*4096
    float* Off   = Aout  + 4 * 4096;                      // 256

    k1_gram <<<dim3(PB, GROUPS), 512, 0, stream>>>(X, pGram, pSum);
    k2a1    <<<dim3(64, GROUPS, 7), 256, 0, stream>>>(pGram, pSum, pG2, pS2);
    k2b_ns  <<<dim3(GROUPS), 256, 0, stream>>>(pG2, pS2, Wt, Bs, Aout, Off);
    k3_apply<<<dim3(1568, GROUPS), 256, 0, stream>>>(X, Aout, Off, Y);
}

// Round 16
// 78.736 us; speedup vs baseline: 1.0359x; 1.0359x over previous
//
#include <hip/hip_runtime.h>
#include <math.h>

#define GROUPS 4
#define DCH    64
#define NBATCH 32
#define CTOT   256
#define HW     3136
#define CHW    (CTOT*HW)        /* 802816 */
#define MTOT   (NBATCH*HW)      /* 100352 */
#define PB     196              /* partial k-blocks per group */
#define EPSV   1e-5f

typedef __attribute__((ext_vector_type(8))) short bf16x8;
typedef __attribute__((ext_vector_type(4))) float f32x4;

__device__ __forceinline__ f32x4 mfma16(bf16x8 a, bf16x8 b, f32x4 c) {
    return __builtin_amdgcn_mfma_f32_16x16x32_bf16(a, b, c, 0, 0, 0);
}

// truncation split: x = hi + lo (exact), bf16(hi), bf16(lo); err <= 2^-16 |x|
__device__ __forceinline__ void split2(float x, short& h, short& l) {
    union { float f; unsigned u; } c; c.f = x;
    h = (short)(c.u >> 16);
    union { unsigned u; float f; } hm; hm.u = c.u & 0xFFFF0000u;
    union { float f; unsigned u; } lo; lo.f = x - hm.f;
    l = (short)(lo.u >> 16);
}

__device__ __forceinline__ void load_slab(const float* bp, float dst[16]) {
    float4 a0 = *reinterpret_cast<const float4*>(bp);
    float4 a1 = *reinterpret_cast<const float4*>(bp + 4);
    float4 b0 = *reinterpret_cast<const float4*>(bp + 32);
    float4 b1 = *reinterpret_cast<const float4*>(bp + 36);
    dst[0]=a0.x; dst[1]=a0.y; dst[2]=a0.z;  dst[3]=a0.w;
    dst[4]=a1.x; dst[5]=a1.y; dst[6]=a1.z;  dst[7]=a1.w;
    dst[8]=b0.x; dst[9]=b0.y; dst[10]=b0.z; dst[11]=b0.w;
    dst[12]=b1.x; dst[13]=b1.y; dst[14]=b1.z; dst[15]=b1.w;
}

// ---------------------------------------------------------------------------
// K1: per-group partial Gram (R14 form — best measured). Wave (tr,par) loads
// only its own 16-row slab, shares packed hi/lo fragments via TRUE
// double-buffered frag LDS (2 x 32KB halves, fb=(t&1)*8192), ONE barrier
// per step. 66KB LDS -> 2 blocks/CU.
// ---------------------------------------------------------------------------
__global__ __launch_bounds__(512) void k1_gram(const float* __restrict__ X,
                                               float* __restrict__ pGram,
                                               float* __restrict__ pSum)
{
    constexpr int KPB = MTOT / PB;      // 512 cols per block
    constexpr int NST = KPB / 128;      // 4 steps (even -> final fb = 8192)
    const int pb   = blockIdx.x;
    const int g    = blockIdx.y;
    const int tid  = threadIdx.x;       // 0..511
    const int w    = tid >> 6;
    const int lane = tid & 63;
    const int tr   = w & 3;             // slab this wave owns
    const int par  = w >> 2;            // 64-col half of the 128-col step
    const int lr   = lane & 15;
    const int q    = lane >> 4;

    __shared__ float smem[16384];       // 2 x 32KB frag buffers; epilogue overlays [0..8191]
    __shared__ float rsum[2][64];

    f32x4 acc[4];
#pragma unroll
    for (int c = 0; c < 4; ++c) acc[c] = (f32x4)(0.f);
    float sumv = 0.f;

    const float* Xg  = X + (size_t)g * DCH * HW;
    const int    row = 16 * tr + lr;

    float xv[2][16];
    // prologue: issue step 0
    {
        const int kk = pb * KPB + par * 64;
        const int n  = kk / HW;
        const int s  = kk - n * HW;
        load_slab(Xg + (size_t)n * CHW + (size_t)row * HW + s + q * 8, xv[0]);
    }

#pragma unroll
    for (int t = 0; t < NST; ++t) {
        const int fb = (t & 1) * 8192;  // this step's frag buffer half
        // 1) issue step t+1 loads first (independent of step-t pack)
        if (t + 1 < NST) {
            const int kk = pb * KPB + (t + 1) * 128 + par * 64;
            const int n  = kk / HW;
            const int s  = kk - n * HW;
            load_slab(Xg + (size_t)n * CHW + (size_t)row * HW + s + q * 8,
                      xv[(t + 1) & 1]);
        }
        // 2) pack own fragments for step t
        bf16x8 ah[2], al[2];
#pragma unroll
        for (int ks = 0; ks < 2; ++ks) {
#pragma unroll
            for (int j = 0; j < 8; ++j) {
                float x = xv[t & 1][ks * 8 + j];
                sumv += x;
                short h, l; split2(x, h, l);
                ah[ks][j] = h; al[ks][j] = l;
            }
        }
        // 3) publish: slot = ((par*4+slab)*2+ks)*2+hl, 1KB/slot, lane-linear
#pragma unroll
        for (int ks = 0; ks < 2; ++ks) {
            *reinterpret_cast<bf16x8*>(&smem[fb + (((par*4+tr)*2+ks)*2+0)*256 + lane*4]) = ah[ks];
            *reinterpret_cast<bf16x8*>(&smem[fb + (((par*4+tr)*2+ks)*2+1)*256 + lane*4]) = al[ks];
        }
        __syncthreads();
        // 4) consume all 4 slabs (no trailing barrier: next publish -> other half)
#pragma unroll
        for (int c = 0; c < 4; ++c) {
#pragma unroll
            for (int ks = 0; ks < 2; ++ks) {
                bf16x8 bh = *reinterpret_cast<const bf16x8*>(
                    &smem[fb + (((par*4+c)*2+ks)*2+0)*256 + lane*4]);
                bf16x8 bl = *reinterpret_cast<const bf16x8*>(
                    &smem[fb + (((par*4+c)*2+ks)*2+1)*256 + lane*4]);
                acc[c] = mfma16(ah[ks], bh, acc[c]);
                acc[c] = mfma16(ah[ks], bl, acc[c]);
                acc[c] = mfma16(al[ks], bh, acc[c]);
            }
        }
    }

    // row sums: reduce over q-quarters
    sumv += __shfl_xor(sumv, 16);
    sumv += __shfl_xor(sumv, 32);
    if (q == 0) rsum[par][row] = sumv;

    // parity-split Gram partial into overlay [0..8191] — disjoint from the
    // final step's frag half (fb=8192 since NST even).
#pragma unroll
    for (int c = 0; c < 4; ++c) {
#pragma unroll
        for (int r = 0; r < 4; ++r) {
            smem[par * 4096 + (16 * tr + 4 * q + r) * 64 + 16 * c + lr] = acc[c][r];
        }
    }
    __syncthreads();

    float* pg = pGram + ((size_t)g * PB + pb) * 4096;
    for (int i = tid; i < 4096; i += 512) pg[i] = smem[i] + smem[4096 + i];
    if (tid < 64)
        pSum[((size_t)g * PB + pb) * 64 + tid] = rsum[0][tid] + rsum[1][tid];
}

// ---------------------------------------------------------------------------
// K2a1: first-level reduce of partials. Grid (64, 4, 7): block (cb,g,s)
// reduces 28 pbs (7 per thread-quarter, compile-time -> batched loads).
// ---------------------------------------------------------------------------
__global__ __launch_bounds__(256) void k2a1(const float* __restrict__ pGram,
                                            const float* __restrict__ pSum,
                                            float* __restrict__ pG2,
                                            float* __restrict__ pS2)
{
    constexpr int SLICE = PB / 7;       // 28
    const int cb  = blockIdx.x;   // 0..63
    const int g   = blockIdx.y;
    const int s   = blockIdx.z;   // 0..6
    const int tid = threadIdx.x;
    const int e = tid & 63, q = tid >> 6;
    __shared__ float red[4][64];
    __shared__ float red2[4][64];

    const float* pg = pGram + ((size_t)g * PB + s * SLICE + q) * 4096 + cb * 64 + e;
    float sum = 0.f;
#pragma unroll
    for (int i = 0; i < SLICE / 4; ++i)
        sum += pg[(size_t)i * 4 * 4096];
    red[q][e] = sum;
    if (cb == 0) {
        const float* ps = pSum + ((size_t)g * PB + s * SLICE + q) * 64 + e;
        float s2 = 0.f;
#pragma unroll
        for (int i = 0; i < SLICE / 4; ++i)
            s2 += ps[i * 4 * 64];
        red2[q][e] = s2;
    }
    __syncthreads();
    if (tid < 64) {
        pG2[((size_t)g * 7 + s) * 4096 + cb * 64 + tid] =
            red[0][tid] + red[1][tid] + red[2][tid] + red[3][tid];
        if (cb == 0)
            pS2[((size_t)g * 7 + s) * 64 + tid] =
                red2[0][tid] + red2[1][tid] + red2[2][tid] + red2[3][tid];
    }
}

// ---------------------------------------------------------------------------
// K2b: fused final-reduce + Newton-Schulz on the matrix pipe.
//  iter 1 closed-form; iters 2..5 shared-A stage1 (P2, PS) + stage2
//  P2*PS^T; Sn B-fragments hoisted to registers (loop-invariant).
// ---------------------------------------------------------------------------
__device__ __forceinline__ void packrow2(const float* __restrict__ M, int row, int q,
                                         bf16x8& h0, bf16x8& l0,
                                         bf16x8& h1, bf16x8& l1)
{
    const float* p = M + row * 68 + 8 * q;
    float4 a0 = *reinterpret_cast<const float4*>(p);
    float4 a1 = *reinterpret_cast<const float4*>(p + 4);
    float4 b0 = *reinterpret_cast<const float4*>(p + 32);
    float4 b1 = *reinterpret_cast<const float4*>(p + 36);
    float e0[8] = {a0.x, a0.y, a0.z, a0.w, a1.x, a1.y, a1.z, a1.w};
    float e1[8] = {b0.x, b0.y, b0.z, b0.w, b1.x, b1.y, b1.z, b1.w};
#pragma unroll
    for (int j = 0; j < 8; ++j) {
        short h, l;
        split2(e0[j], h, l); h0[j] = h; l0[j] = l;
        split2(e1[j], h, l); h1[j] = h; l1[j] = l;
    }
}

__global__ __launch_bounds__(256) void k2b_ns(const float* __restrict__ pG2,
                                              const float* __restrict__ pS2,
                                              const float* __restrict__ Wt,
                                              const float* __restrict__ Bs,
                                              float* __restrict__ Aout,
                                              float* __restrict__ Off)
{
    const int g   = blockIdx.x;
    const int tid = threadIdx.x;
    const int w = tid >> 6, lane = tid & 63, lr = lane & 15, q = lane >> 4;
    __shared__ float MP[64 * 68];
    __shared__ float MA[64 * 68];    // P2
    __shared__ float MB2[64 * 68];   // PS
    __shared__ float MS[64 * 68];    // Sn
    __shared__ float lmean[64];
    __shared__ float redm[1024];
    __shared__ float rtr_s;

    if (tid < 64) {
        float s2 = 0.f;
#pragma unroll
        for (int s = 0; s < 7; ++s) s2 += pS2[((size_t)g * 7 + s) * 64 + tid];
        lmean[tid] = s2 * (1.0f / (float)MTOT);
    }
    __syncthreads();
    for (int idx = tid; idx < 4096; idx += 256) {
        int d = idx >> 6, e = idx & 63;
        float sum = 0.f;
#pragma unroll
        for (int s = 0; s < 7; ++s) sum += pG2[((size_t)g * 7 + s) * 4096 + idx];
        float v = sum * (1.0f / (float)MTOT) - lmean[d] * lmean[e];
        if (d == e) v += EPSV;
        MS[d * 68 + e] = v;
    }
    __syncthreads();
    if (tid < 64) {
        float v = MS[tid * 68 + tid];
#pragma unroll
        for (int off = 32; off > 0; off >>= 1) v += __shfl_down(v, off);
        if (tid == 0) rtr_s = 1.f / v;
    }
    __syncthreads();
    const float rTr = rtr_s;
    for (int idx = tid; idx < 4096; idx += 256) {
        int d = idx >> 6, e = idx & 63;
        float sv = MS[d * 68 + e] * rTr;
        MS[d * 68 + e] = sv;
        MP[d * 68 + e] = ((d == e) ? 1.5f : 0.f) - 0.5f * sv;
    }
    __syncthreads();

    // hoist loop-invariant Sn B-fragments into registers
    bf16x8 snh0[4], snl0[4], snh1[4], snl1[4];
#pragma unroll
    for (int c = 0; c < 4; ++c)
        packrow2(MS, 16 * c + lr, q, snh0[c], snl0[c], snh1[c], snl1[c]);

    const int row_o = 16 * w + 4 * q;
    for (int it = 0; it < 4; ++it) {
        f32x4 a2[4], aS[4];
#pragma unroll
        for (int c = 0; c < 4; ++c) { a2[c] = (f32x4)(0.f); aS[c] = (f32x4)(0.f); }
        bf16x8 pah0, pal0, pah1, pal1;
        packrow2(MP, 16 * w + lr, q, pah0, pal0, pah1, pal1);
#pragma unroll
        for (int c = 0; c < 4; ++c) {
            bf16x8 bh0, bl0, bh1, bl1;
            packrow2(MP, 16 * c + lr, q, bh0, bl0, bh1, bl1);
            a2[c] = mfma16(pah0, bh0, a2[c]);
            a2[c] = mfma16(pah0, bl0, a2[c]);
            a2[c] = mfma16(pal0, bh0, a2[c]);
            a2[c] = mfma16(pah1, bh1, a2[c]);
            a2[c] = mfma16(pah1, bl1, a2[c]);
            a2[c] = mfma16(pal1, bh1, a2[c]);
            aS[c] = mfma16(pah0, snh0[c], aS[c]);
            aS[c] = mfma16(pah0, snl0[c], aS[c]);
            aS[c] = mfma16(pal0, snh0[c], aS[c]);
            aS[c] = mfma16(pah1, snh1[c], aS[c]);
            aS[c] = mfma16(pah1, snl1[c], aS[c]);
            aS[c] = mfma16(pal1, snh1[c], aS[c]);
        }
#pragma unroll
        for (int c = 0; c < 4; ++c)
#pragma unroll
            for (int r = 0; r < 4; ++r) {
                MA [(row_o + r) * 68 + 16 * c + lr] = a2[c][r];
                MB2[(row_o + r) * 68 + 16 * c + lr] = aS[c][r];
            }
        __syncthreads();

        f32x4 acc[4];
#pragma unroll
        for (int c = 0; c < 4; ++c) acc[c] = (f32x4)(0.f);
        bf16x8 qah0, qal0, qah1, qal1;
        packrow2(MA, 16 * w + lr, q, qah0, qal0, qah1, qal1);
#pragma unroll
        for (int c = 0; c < 4; ++c) {
            bf16x8 bh0, bl0, bh1, bl1;
            packrow2(MB2, 16 * c + lr, q, bh0, bl0, bh1, bl1);
            acc[c] = mfma16(qah0, bh0, acc[c]);
            acc[c] = mfma16(qah0, bl0, acc[c]);
            acc[c] = mfma16(qal0, bh0, acc[c]);
            acc[c] = mfma16(qah1, bh1, acc[c]);
            acc[c] = mfma16(qah1, bl1, acc[c]);
            acc[c] = mfma16(qal1, bh1, acc[c]);
        }
#pragma unroll
        for (int c = 0; c < 4; ++c)
#pragma unroll
            for (int r = 0; r < 4; ++r) {
                int o = (row_o + r) * 68 + 16 * c + lr;
                MP[o] = 1.5f * MP[o] - 0.5f * acc[c][r];
            }
        __syncthreads();
    }

    const float sc = sqrtf(rTr);
    const int i0 = (tid >> 4) << 2, j0 = (tid & 15) << 2;
#pragma unroll
    for (int i = 0; i < 4; ++i) {
        int d = i0 + i;
        float wv = Wt[g * 64 + d] * sc;
        float4 v;
        v.x = MP[d * 68 + j0 + 0] * wv;
        v.y = MP[d * 68 + j0 + 1] * wv;
        v.z = MP[d * 68 + j0 + 2] * wv;
        v.w = MP[d * 68 + j0 + 3] * wv;
        *reinterpret_cast<float4*>(Aout + g * 4096 + (d << 6) + j0) = v;
        redm[(d << 4) + (tid & 15)] =
            v.x * lmean[j0] + v.y * lmean[j0 + 1] + v.z * lmean[j0 + 2] + v.w * lmean[j0 + 3];
    }
    __syncthreads();
    if (tid < 64) {
        float s = 0.f;
#pragma unroll
        for (int qq = 0; qq < 16; ++qq) s += redm[(tid << 4) + qq];
        Off[g * 64 + tid] = Bs[g * 64 + tid] - s;
    }
}

// ---------------------------------------------------------------------------
// K3: out = A'(x) + off (R14 staged form — best measured). ONE 64-col chunk
// per block, grid (1568,4), LDS-staged tile, dwordx4 loads AND stores, one
// barrier. Measured A/B: staged 37.5us < direct-b128 40us (R15) <
// direct-dword 66us (R12) — staging dedups L2 request pressure at
// 8 blocks/CU where cache absorption is no longer free.
// ---------------------------------------------------------------------------
__global__ __launch_bounds__(256) void k3_apply(const float* __restrict__ X,
                                                const float* __restrict__ Aout,
                                                const float* __restrict__ Off,
                                                float* __restrict__ Y)
{
    const int c    = blockIdx.x;        // 0..1567
    const int g    = blockIdx.y;
    const int tid  = threadIdx.x;
    const int w    = tid >> 6;          // output row block 16w
    const int lane = tid & 63;
    const int lr   = lane & 15;
    const int q    = lane >> 4;

    __shared__ float tile[4096];        // 16 KB x-tile

    const int col0 = c * 64;            // never crosses sample (HW%64==0)
    const int n    = col0 / HW;
    const int s0   = col0 - n * HW;
    const float* Xg   = X + (size_t)g * DCH * HW;
    const float* base = Xg + (size_t)n * CHW + s0;

    // 1) issue the 4 staging loads
    float4 xr[4];
#pragma unroll
    for (int k = 0; k < 4; ++k) {
        int f = k * 256 + tid, r = f >> 4, gc = f & 15;
        xr[k] = *reinterpret_cast<const float4*>(base + (size_t)r * HW + gc * 4);
    }

    // 2) load+pack A' fragments and offsets under the staging loads' shadow
    bf16x8 ah[2], al[2];
#pragma unroll
    for (int s = 0; s < 2; ++s) {
        const float* ap = Aout + g * 4096 + (16 * w + lr) * 64 + 32 * s + 8 * q;
        float4 v0 = *reinterpret_cast<const float4*>(ap);
        float4 v1 = *reinterpret_cast<const float4*>(ap + 4);
        float av[8] = {v0.x, v0.y, v0.z, v0.w, v1.x, v1.y, v1.z, v1.w};
#pragma unroll
        for (int j = 0; j < 8; ++j) {
            short h, l; split2(av[j], h, l);
            ah[s][j] = h; al[s][j] = l;
        }
    }
    float offv[4];
#pragma unroll
    for (int r = 0; r < 4; ++r) offv[r] = Off[g * 64 + 16 * w + 4 * q + r];

    // 3) stage to LDS, one barrier
#pragma unroll
    for (int k = 0; k < 4; ++k) {
        int f = k * 256 + tid;
        *reinterpret_cast<float4*>(&tile[f * 4]) = xr[k];
    }
    __syncthreads();

    // 4) compute
    f32x4 accg[4];
#pragma unroll
    for (int j = 0; j < 4; ++j) accg[j] = (f32x4)(0.f);

#pragma unroll
    for (int ks = 0; ks < 2; ++ks) {
        bf16x8 bh[4], bl[4];
#pragma unroll
        for (int j8 = 0; j8 < 8; ++j8) {
            const int row = 32 * ks + 8 * q + j8;
            float4 v = *reinterpret_cast<const float4*>(&tile[row * 64 + lr * 4]);
            float vv[4] = {v.x, v.y, v.z, v.w};
#pragma unroll
            for (int jj = 0; jj < 4; ++jj) {
                short h, l; split2(vv[jj], h, l);
                bh[jj][j8] = h; bl[jj][j8] = l;
            }
        }
#pragma unroll
        for (int jj = 0; jj < 4; ++jj) {
            accg[jj] = mfma16(ah[ks], bh[jj], accg[jj]);
            accg[jj] = mfma16(ah[ks], bl[jj], accg[jj]);
            accg[jj] = mfma16(al[ks], bh[jj], accg[jj]);
        }
    }

    // 5) store
    float* yp = Y + (size_t)g * DCH * HW + (size_t)n * CHW + s0 + 4 * lr;
#pragma unroll
    for (int r = 0; r < 4; ++r) {
        int row = 16 * w + 4 * q + r;
        float4 o;
        o.x = accg[0][r] + offv[r];
        o.y = accg[1][r] + offv[r];
        o.z = accg[2][r] + offv[r];
        o.w = accg[3][r] + offv[r];
        *reinterpret_cast<float4*>(yp + (size_t)row * HW) = o;
    }
}

// ---------------------------------------------------------------------------
extern "C" void kernel_launch(void* const* d_in, const int* in_sizes, int n_in,
                              void* d_out, int out_size, void* d_ws, size_t ws_size,
                              hipStream_t stream)
{
    const float* X  = (const float*)d_in[0];
    const float* Wt = (const float*)d_in[1];
    const float* Bs = (const float*)d_in[2];
    float* Y  = (float*)d_out;
    float* ws = (float*)d_ws;

    float* pGram = ws;                                    // 4*PB*4096
    float* pSum  = pGram + (size_t)4 * PB * 4096;         // 4*PB*64
    float* pG2   = pSum  + (size_t)4 * PB * 64;           // 4*7*4096
    float* pS2   = pG2   + (size_t)4 * 7 * 4096;          // 4*7*64
    float* Aout  = pS2   + (size_t)4 * 7 * 64;            // 4*4096
    float* Off   = Aout  + 4 * 4096;                      // 256

    k1_gram <<<dim3(PB, GROUPS), 512, 0, stream>>>(X, pGram, pSum);
    k2a1    <<<dim3(64, GROUPS, 7), 256, 0, stream>>>(pGram, pSum, pG2, pS2);
    k2b_ns  <<<dim3(GROUPS), 256, 0, stream>>>(pG2, pS2, Wt, Bs, Aout, Off);
    k3_apply<<<dim3(1568, GROUPS), 256, 0, stream>>>(X, Aout, Off, Y);
}